// Round 9
// baseline (180.122 us; speedup 1.0000x reference)
//
#include <hip/hip_runtime.h>

#define XS 128
#define PLANE (XS * XS)            // 16384
#define X3 (XS * XS * XS)          // 2097152
#define ZC 4                       // owned planes per chunk
#define TPB 1024                   // fused block size (16 waves)
#define SLOTS 4                    // prefetch slots: SLOTS*TPB = 4096 >= typical bin
#define QPT 4                      // float4 quads per thread = PLANE/4/TPB
#define CAP 8192                   // fixed capacity per z-bin (max bin ~4100)

// Barrier draining LDS only (lgkmcnt), NOT vmcnt: prefetched global loads stay
// in flight across it.
__device__ __forceinline__ void bar_lgkm() {
    __builtin_amdgcn_sched_barrier(0);
    asm volatile("s_waitcnt lgkmcnt(0)" ::: "memory");
    __builtin_amdgcn_s_barrier();
    __builtin_amdgcn_sched_barrier(0);
}

// ---------------------------------------------------------------------------
// Init: zero the 128 bin cursors and the output.
// ---------------------------------------------------------------------------
__global__ __launch_bounds__(256) void init_kernel(
    int* __restrict__ cursor, float* __restrict__ out, int osz)
{
    const int t = threadIdx.x;
    if (t < XS) cursor[t] = 0;
    if (t < osz) out[t] = 0.f;
}

// ---------------------------------------------------------------------------
// Reorder + value-permute (no hist/scan): each z-bin owns slots
// [z*CAP, z*CAP+CAP). Per 4-entry thread: dense float4 reads of all 16 batch
// value rows, register transpose, one fully-used 64B pvT line per entry,
// plus posArr[slot] = (y<<7)|x as u16.
// ---------------------------------------------------------------------------
__global__ __launch_bounds__(256) void reorder_kernel(
    const int* __restrict__ idx, int* __restrict__ cursor,
    const float* __restrict__ vals, float* __restrict__ pvT,
    unsigned short* __restrict__ posArr, int N)
{
    __shared__ int lh[XS], lbase[XS];
    const int c0 = blockIdx.x * 1024;           // 256 threads * 4 entries
    const int t = threadIdx.x;
    int z[4], key[4];
    int cntm = 0;
    const bool fast = (c0 + 1024 <= N);

    for (int i = t; i < XS; i += 256) lh[i] = 0;

    if (fast) {                                 // vectorized index read
        const int4* p = (const int4*)(idx + (size_t)c0 * 3);
        int4 A = p[3 * t], B4 = p[3 * t + 1], C = p[3 * t + 2];
        z[0] = A.x;  key[0] = (A.y << 7) | A.z;
        z[1] = A.w;  key[1] = (B4.x << 7) | B4.y;
        z[2] = B4.z; key[2] = (B4.w << 7) | C.x;
        z[3] = C.y;  key[3] = (C.z << 7) | C.w;
        cntm = 4;
    } else {                                    // guarded tail block
        #pragma unroll
        for (int i = 0; i < 4; ++i) {
            const int n = c0 + 4 * t + i;
            if (n < N) {
                z[cntm]   = idx[3 * n];
                key[cntm] = (idx[3 * n + 1] << 7) | idx[3 * n + 2];
                ++cntm;
            }
        }
    }
    __syncthreads();
    #pragma unroll
    for (int i = 0; i < 4; ++i)
        if (i < cntm) atomicAdd(&lh[z[i]], 1);
    __syncthreads();
    for (int i = t; i < XS; i += 256) {
        lbase[i] = lh[i] ? atomicAdd(&cursor[i], lh[i]) : 0;
        lh[i] = 0;
    }
    __syncthreads();

    int slot[4];
    #pragma unroll
    for (int i = 0; i < 4; ++i)
        if (i < cntm) {
            const int r = atomicAdd(&lh[z[i]], 1);
            slot[i] = z[i] * CAP + lbase[z[i]] + r;
            posArr[slot[i]] = (unsigned short)key[i];
        }

    if (fast) {
        float4 vv[16];                          // vals[b][c0+4t .. +3], dense
        #pragma unroll
        for (int b = 0; b < 16; ++b)
            vv[b] = *(const float4*)(vals + (size_t)b * N + c0 + 4 * t);
        #pragma unroll
        for (int i = 0; i < 4; ++i) {           // one 64B line per entry
            float4* dst = (float4*)(pvT + (size_t)slot[i] * 16);
            float4 w0 = make_float4(((const float*)&vv[0])[i],  ((const float*)&vv[1])[i],
                                    ((const float*)&vv[2])[i],  ((const float*)&vv[3])[i]);
            float4 w1 = make_float4(((const float*)&vv[4])[i],  ((const float*)&vv[5])[i],
                                    ((const float*)&vv[6])[i],  ((const float*)&vv[7])[i]);
            float4 w2 = make_float4(((const float*)&vv[8])[i],  ((const float*)&vv[9])[i],
                                    ((const float*)&vv[10])[i], ((const float*)&vv[11])[i]);
            float4 w3 = make_float4(((const float*)&vv[12])[i], ((const float*)&vv[13])[i],
                                    ((const float*)&vv[14])[i], ((const float*)&vv[15])[i]);
            dst[0] = w0; dst[1] = w1; dst[2] = w2; dst[3] = w3;
        }
    } else {
        for (int i = 0; i < cntm; ++i) {
            const int n = c0 + 4 * t + i;
            float* dst = pvT + (size_t)slot[i] * 16;
            for (int b = 0; b < 16; ++b) dst[b] = vals[(size_t)b * N + n];
        }
    }
}

// ---------------------------------------------------------------------------
// Fused: block = (b, z-chunk of ZC planes). Single 64 KB LDS plane (2 blk/CU
// -> 32 waves/CU); previous plane carried in registers for the z-diff.
// Gather = two INDEPENDENT dense streams: posArr (u16) and pvT strided 64B
// (consecutive lines). lgkm-only barriers keep prefetch loads in flight.
// ---------------------------------------------------------------------------
__global__ __launch_bounds__(TPB, 8) void fused_kernel(
    const unsigned short* __restrict__ posArr, const int* __restrict__ cnt,
    const float* __restrict__ pvT, float* __restrict__ out, int Btot)
{
    __shared__ float buf[PLANE];                // 64 KB
    __shared__ float rtv[TPB / 64], rms[TPB / 64];

    const int b   = blockIdx.x;
    const int z0  = blockIdx.y * ZC;
    const int tid = threadIdx.x;
    const int pmax = (z0 + ZC < XS) ? (z0 + ZC) : (XS - 1);

    int pos[SLOTS]; float val[SLOTS];
    int pc = 0, ps0 = 0;

    auto prefetch = [&](int zp) {
        ps0 = zp * CAP; pc = cnt[zp];
        #pragma unroll
        for (int i = 0; i < SLOTS; ++i) {
            const int sx = ps0 + tid + i * TPB;             // within region
            pos[i] = posArr[sx] & (PLANE - 1);              // mask garbage tail
            val[i] = pvT[(size_t)sx * 16 + b];              // stride-64B burst
        }
    };
    auto scatter = [&]() {
        #pragma unroll
        for (int i = 0; i < SLOTS; ++i) {
            const float v = (tid + i * TPB < pc) ? val[i] : 0.f;
            atomicAdd(&buf[pos[i]], v);
        }
        for (int e = SLOTS * TPB + tid; e < pc; e += TPB) { // rare overflow
            atomicAdd(&buf[posArr[ps0 + e] & (PLANE - 1)],
                      pvT[(size_t)(ps0 + e) * 16 + b]);
        }
    };

    // prologue: build plane z0, prefetch z0+1
    prefetch(z0);
    #pragma unroll
    for (int i = 0; i < QPT; ++i)
        ((float4*)buf)[tid + i * TPB] = make_float4(0.f, 0.f, 0.f, 0.f);
    bar_lgkm();
    scatter();
    prefetch(z0 + 1);
    bar_lgkm();

    float4 prev[QPT];
    float tv = 0.f, ms = 0.f;

    for (int p = z0; p <= pmax; ++p) {
        float4 a[QPT];
        #pragma unroll
        for (int i = 0; i < QPT; ++i)
            a[i] = ((const float4*)buf)[tid + i * TPB];

        if (p > z0) {                           // z-diff pair (p-1, p)
            #pragma unroll
            for (int i = 0; i < QPT; ++i) {
                float d;
                d = a[i].x - prev[i].x; tv += fabsf(d); ms += d * d;
                d = a[i].y - prev[i].y; tv += fabsf(d); ms += d * d;
                d = a[i].z - prev[i].z; tv += fabsf(d); ms += d * d;
                d = a[i].w - prev[i].w; tv += fabsf(d); ms += d * d;
            }
        }
        if (p < z0 + ZC) {                      // owned plane: x/y diffs
            #pragma unroll
            for (int i = 0; i < QPT; ++i) {
                const int q = tid + i * TPB;
                const int qx = q & 31, y = q >> 5;
                float d;
                d = a[i].y - a[i].x; tv += fabsf(d); ms += d * d;
                d = a[i].z - a[i].y; tv += fabsf(d); ms += d * d;
                d = a[i].w - a[i].z; tv += fabsf(d); ms += d * d;
                if (qx < 31) {
                    d = buf[4 * q + 4] - a[i].w; tv += fabsf(d); ms += d * d;
                }
                if (y < XS - 1) {
                    const float4 u = ((const float4*)buf)[q + 32];
                    d = u.x - a[i].x; tv += fabsf(d); ms += d * d;
                    d = u.y - a[i].y; tv += fabsf(d); ms += d * d;
                    d = u.z - a[i].z; tv += fabsf(d); ms += d * d;
                    d = u.w - a[i].w; tv += fabsf(d); ms += d * d;
                }
            }
        }
        #pragma unroll
        for (int i = 0; i < QPT; ++i) prev[i] = a[i];

        if (p < pmax) {
            bar_lgkm();                         // all reads of buf done
            #pragma unroll
            for (int i = 0; i < QPT; ++i)
                ((float4*)buf)[tid + i * TPB] = make_float4(0.f, 0.f, 0.f, 0.f);
            bar_lgkm();                         // zero done
            scatter();                          // build plane p+1
            if (p + 2 <= pmax) prefetch(p + 2);
            bar_lgkm();                         // plane p+1 built
        }
    }

    for (int o = 32; o > 0; o >>= 1) {
        tv += __shfl_down(tv, o); ms += __shfl_down(ms, o);
    }
    if ((tid & 63) == 0) { rtv[tid >> 6] = tv; rms[tid >> 6] = ms; }
    __syncthreads();
    if (tid == 0) {
        float t = 0.f, m = 0.f;
        #pragma unroll
        for (int w = 0; w < TPB / 64; ++w) { t += rtv[w]; m += rms[w]; }
        atomicAdd(out + b,        t * (1.0f / (float)X3));
        atomicAdd(out + Btot + b, m * (1.0f / (float)(2 * XS * XS - 2 * XS)));
    }
}

extern "C" void kernel_launch(void* const* d_in, const int* in_sizes, int n_in,
                              void* d_out, int out_size, void* d_ws, size_t ws_size,
                              hipStream_t stream)
{
    const int*   indices = (const int*)d_in[0];
    const float* values  = (const float*)d_in[1];
    const int N = in_sizes[0] / 3;          // 500000
    const int B = in_sizes[1] / N;          // 16
    float* out = (float*)d_out;
    char*  ws  = (char*)d_ws;

    // ws layout: [pvT 128*CAP*16 f32 = 64MB][posArr 128*CAP u16 = 2MB][cursor]
    float* pvT = (float*)ws;
    unsigned short* posArr = (unsigned short*)(ws + (size_t)XS * CAP * 16 * sizeof(float));
    int* cursor = (int*)((char*)posArr + (size_t)XS * CAP * sizeof(unsigned short));

    init_kernel<<<1, 256, 0, stream>>>(cursor, out, out_size);
    reorder_kernel<<<(N + 1023) / 1024, 256, 0, stream>>>(
        indices, cursor, values, pvT, posArr, N);
    fused_kernel<<<dim3(B, XS / ZC), TPB, 0, stream>>>(
        posArr, cursor, pvT, out, B);
}